// Round 12
// baseline (245.545 us; speedup 1.0000x reference)
//
#include <hip/hip_runtime.h>
#include <stdint.h>

typedef float f32x4 __attribute__((ext_vector_type(4)));
typedef __bf16 bf16x8 __attribute__((ext_vector_type(8)));
typedef unsigned short u16;
typedef u16 u16x8 __attribute__((ext_vector_type(8)));

__device__ __forceinline__ u16 f2bf(float f) {
  uint32_t u = __builtin_bit_cast(uint32_t, f);
  return (u16)((u + 0x7fffu + ((u >> 16) & 1u)) >> 16);
}
__device__ __forceinline__ float bf2f(u16 h) {
  uint32_t u = ((uint32_t)h) << 16;
  return __builtin_bit_cast(float, u);
}
__device__ __forceinline__ float elup1(float x) {
  return x > 0.f ? x + 1.f : __expf(x);
}
__device__ __forceinline__ void gll16(const void* g, void* l) {
  __builtin_amdgcn_global_load_lds(
      (const __attribute__((address_space(1))) unsigned int*)g,
      (__attribute__((address_space(3))) unsigned int*)l, 16, 0, 0);
}

#define BAR() __builtin_amdgcn_s_barrier()
#define VMC(n) asm volatile("s_waitcnt vmcnt(" #n ")" ::: "memory")

// ---------------- fused f32 -> bf16 conversion (x + w_qkv) ---------------
__global__ void cvt_all_kernel(const float* __restrict__ x, u16* __restrict__ xb,
                               const float* __restrict__ wq, u16* __restrict__ wqb) {
  int i = blockIdx.x * 256 + threadIdx.x;  // float4 index, 4980736 total
  if (i >= 4980736) return;
  const float* in;
  u16* out;
  if (i < 4194304) {
    in = x; out = xb;
  } else {
    in = wq; out = wqb; i -= 4194304;
  }
  float4 f = ((const float4*)in)[i];
  ushort4 o;
  o.x = f2bf(f.x); o.y = f2bf(f.y); o.z = f2bf(f.z); o.w = f2bf(f.w);
  ((ushort4*)out)[i] = o;
}

// ============ 256x256 bf16 GEMM  C[M,N] = A[M,K]*B[N,K]^T =================
// r8 configuration (best measured: 906 TF, MfmaUtil 37.9%) — the m97-class
// plain-HIP plateau, reproduced across 6 schedule variants. 512 threads
// (8 waves, 2M x 4N; wave tile 128x64). BK=64. LDS 128 KiB (2 dbuf), one
// vmcnt(0)+barrier per K-tile, both A-half frag sets live, parity stagger.
// Swizzle: stored colbyte = logical colbyte ^ ((ldsrow&7)<<4); gll dest
// linear, source pre-swizzled (rule #21).
// lda parametrized (out-proj reads q' cols of qkvb, lda=3072).
// bstep: B advances per 16 M-tiles (per-batch W2T); 0 = shared B.
// EPI==0: qkv epilogue (bias + elu+1, bf16 store, LDS-coalesced)
// EPI==1: out epilogue (bias, f32 store)
template <int EPI>
__global__ __launch_bounds__(512, 2)
void gemm256(const u16* __restrict__ A, int lda, const u16* __restrict__ B,
             const float* __restrict__ bias, void* __restrict__ Cout,
             int N, int K, int nbj, int bstep) {
  __shared__ __align__(16) u16 lds[65536];  // 128 KiB
  const int tid = threadIdx.x;
  const int wave = tid >> 6, lane = tid & 63;
  const int fr = lane & 15, fq = lane >> 4;
  const int wm = wave >> 2, wn = wave & 3;

  // XCD-aware bijective block swizzle (grid % 8 == 0 by construction)
  const int nwg = gridDim.x;
  const int cpx = nwg >> 3;
  const int swz = (blockIdx.x & 7) * cpx + (blockIdx.x >> 3);
  const int bi = swz / nbj, bj = swz % nbj;

  const u16* Ab = A + (size_t)bi * 256 * lda;
  const u16* Bb = B + (size_t)(bi >> 4) * bstep + (size_t)bj * 256 * K;

  // staging geometry: per inst, thread covers LDS bytes i*8192+wave*1024+lane*16
  const int l8 = lane >> 3;                       // ldsrow & 7
  const int cswz = ((lane & 7) ^ l8) << 3;        // swizzled col offset (elements)
  const int r6 = wave * 8 + l8;                   // row within 64-row inst block

#define STAGE_A(d, h, k0)                                                      \
  { _Pragma("unroll")                                                          \
    for (int i_ = 0; i_ < 2; ++i_) {                                           \
      int gr_ = i_ * 128 + (h) * 64 + r6;                                      \
      gll16(Ab + (size_t)gr_ * lda + (k0) + cswz,                              \
            &lds[((d) * 32768 + (h) * 16384 + i_ * 8192 + wave * 1024) >> 1]); \
    } }

#define STAGE_B(d, h, k0)                                                      \
  { _Pragma("unroll")                                                          \
    for (int i_ = 0; i_ < 2; ++i_) {                                           \
      int r_ = i_ * 64 + r6;                                                   \
      int gr_ = (r_ >> 5) * 64 + (h) * 32 + (r_ & 31);                         \
      gll16(Bb + (size_t)gr_ * K + (k0) + cswz,                                \
            &lds[(65536 + (d) * 32768 + (h) * 16384 + i_ * 8192 + wave * 1024) >> 1]); \
    } }

#define STAGE_ALL(d, k0) \
  { STAGE_A(d, 0, k0); STAGE_A(d, 1, k0); STAGE_B(d, 0, k0); STAGE_B(d, 1, k0); }

  // fragment-read addressing (bytes)
  const int xorc = (fr & 7) << 4;
  const int acol[2] = {(fq * 16) ^ xorc, (64 + fq * 16) ^ xorc};
  const int arow = (wm * 64 + fr) * 128;
  const int brow = (wn * 32 + fr) * 128;

#define LDSV(off) (*(const bf16x8*)&lds[(off) >> 1])

  f32x4 acc[8][4] = {};
  bf16x8 af0[4][2], af1[4][2];  // BOTH A-halves live (no WAR with MFMA)
  bf16x8 bfr[2][2][2];          // B frags [nh][nn][ks], both halves live

#define READ_A(d, mh, dst)                                                     \
  { _Pragma("unroll")                                                          \
    for (int ks = 0; ks < 2; ++ks) {                                           \
      _Pragma("unroll")                                                        \
      for (int mm = 0; mm < 4; ++mm)                                           \
        dst[mm][ks] = LDSV((d) * 32768 + (mh) * 16384 + arow + mm * 2048 + acol[ks]); \
    } }

#define READ_B(d, nh)                                                          \
  { _Pragma("unroll")                                                          \
    for (int ks = 0; ks < 2; ++ks) {                                           \
      _Pragma("unroll")                                                        \
      for (int nn = 0; nn < 2; ++nn)                                           \
        bfr[nh][nn][ks] = LDSV(65536 + (d) * 32768 + (nh) * 16384 + brow + nn * 2048 + acol[ks]); \
    } }

#define MFMA_Q(mh, nh, src)                                                    \
  { __builtin_amdgcn_s_setprio(1);                                             \
    _Pragma("unroll")                                                          \
    for (int ks = 0; ks < 2; ++ks) {                                           \
      _Pragma("unroll")                                                        \
      for (int mm = 0; mm < 4; ++mm) {                                         \
        _Pragma("unroll")                                                      \
        for (int nn = 0; nn < 2; ++nn)                                         \
          acc[(mh) * 4 + mm][(nh) * 2 + nn] = __builtin_amdgcn_mfma_f32_16x16x32_bf16( \
              src[mm][ks], bfr[nh][nn][ks], acc[(mh) * 4 + mm][(nh) * 2 + nn], 0, 0, 0); \
      } }                                                                      \
    __builtin_amdgcn_s_setprio(0); }

  // F = first A-half computed, S = second; parity-staggered across waves.
#define TILE_BODY(F, S, afF, afS, d, t)                                        \
  {                                                                            \
    READ_B(d, 0); READ_B(d, 1); READ_A(d, F, afF);                             \
    MFMA_Q(F, 0, afF);                                                         \
    READ_A(d, S, afS);                                                         \
    MFMA_Q(F, 1, afF);                                                         \
    if ((t) + 1 < NT) STAGE_ALL((d) ^ 1, ((t) + 1) << 6);                      \
    MFMA_Q(S, 1, afS);                                                         \
    MFMA_Q(S, 0, afS);                                                         \
  }

  const int NT = K >> 6;
  STAGE_ALL(0, 0);
  VMC(0);
  BAR();

  if ((wave & 1) == 0) {
    for (int t = 0; t < NT; ++t) {
      const int d = t & 1;
      TILE_BODY(0, 1, af0, af1, d, t);
      VMC(0); BAR();
    }
  } else {
    for (int t = 0; t < NT; ++t) {
      const int d = t & 1;
      TILE_BODY(1, 0, af1, af0, d, t);
      VMC(0); BAR();
    }
  }

  // ---- epilogue
  const int wrow = wm * 128, wcol = wn * 64;
  if (EPI == 0) {
    const bool do_elu = (bj * 256) < 2048;  // 2048 is 256-aligned
    float bv[4];
#pragma unroll
    for (int n = 0; n < 4; ++n) bv[n] = bias[bj * 256 + wcol + n * 16 + fr];
    u16* wbuf = &lds[wave * 8192];  // wave-private 16 KiB
    const int lrow = lane >> 3, lcol = (lane & 7) * 8;
#pragma unroll
    for (int ch = 0; ch < 2; ++ch) {
#pragma unroll
      for (int m2 = 0; m2 < 4; ++m2)
#pragma unroll
        for (int n = 0; n < 4; ++n)
#pragma unroll
          for (int r = 0; r < 4; ++r) {
            float v = acc[ch * 4 + m2][n][r] + bv[n];
            if (do_elu) v = elup1(v);
            wbuf[(m2 * 16 + fq * 4 + r) * 72 + n * 16 + fr] = f2bf(v);
          }
      // per-wave LDS in-order: read-back safe without barrier
#pragma unroll
      for (int i = 0; i < 8; ++i) {
        bf16x8 val = *(const bf16x8*)&wbuf[(i * 8 + lrow) * 72 + lcol];
        const int rowg = bi * 256 + wrow + ch * 64 + i * 8 + lrow;
        *(bf16x8*)&((u16*)Cout)[(size_t)rowg * N + bj * 256 + wcol + lcol] = val;
      }
    }
  } else {
#pragma unroll
    for (int n = 0; n < 4; ++n) {
      const int colg = bj * 256 + wcol + n * 16 + fr;
      const float bv = bias[colg];
#pragma unroll
      for (int m = 0; m < 8; ++m)
#pragma unroll
        for (int r = 0; r < 4; ++r) {
          const int rowg = bi * 256 + wrow + m * 16 + fq * 4 + r;
          ((float*)Cout)[(size_t)rowg * N + colg] = acc[m][n][r] + bv;
        }
    }
  }
#undef STAGE_A
#undef STAGE_B
#undef STAGE_ALL
#undef READ_A
#undef READ_B
#undef MFMA_Q
#undef TILE_BODY
#undef LDSV
}

// ---------------- kv state partials: kv[d][e] = sum_s k[s,d]*v[s,e] -------
// grid: (64 bh, 8 s-chunks of 512); block 256; 4d x 4e register blocking.
// 32-row LDS tiles. ksum accumulated ONLY by the 16 threads that store it
// (eg==0, t<16): waves 1-3 skip 4 of 20 VALU ops/iter entirely.
__global__ __launch_bounds__(256)
void kv_state_kernel(const u16* __restrict__ qkv, float* __restrict__ pkv,
                     float* __restrict__ pks) {
  const int bh = blockIdx.x, chunk = blockIdx.y;
  const int b = bh >> 4, h = bh & 15;
  const int t = threadIdx.x;
  __shared__ float sK[32][68];
  __shared__ float sV[32][68];
  const int dg = (t & 15) * 4;
  const int eg = (t >> 4) * 4;
  f32x4 acc0 = {}, acc1 = {}, acc2 = {}, acc3 = {};
  f32x4 ak4 = {};
  const size_t rowbase = ((size_t)b * 4096 + (size_t)chunk * 512) * 3072;
  const u16* kp = qkv + rowbase + 1024 + h * 64;
  const u16* vp = qkv + rowbase + 2048 + h * 64;
  // staging: 128 threads K, 128 threads V; 2 x 16B/lane per 32-row tile
  const int lhalf = t >> 7, lr = (t >> 3) & 15, lc = (t & 7) * 8;
  const u16* lsrc = lhalf ? vp : kp;
  float* ldst = lhalf ? &sV[lr][lc] : &sK[lr][lc];
  const bool do_ks = (t < 16);
  for (int s0 = 0; s0 < 512; s0 += 32) {
    u16x8 v8a = *(const u16x8*)&lsrc[(size_t)(s0 + lr) * 3072 + lc];
    u16x8 v8b = *(const u16x8*)&lsrc[(size_t)(s0 + 16 + lr) * 3072 + lc];
#pragma unroll
    for (int j = 0; j < 8; ++j) ldst[j] = bf2f(v8a[j]);
#pragma unroll
    for (int j = 0; j < 8; ++j) ldst[16 * 68 + j] = bf2f(v8b[j]);
    __syncthreads();
    if (do_ks) {
#pragma unroll 4
      for (int sl = 0; sl < 32; ++sl) {
        const f32x4 kv4 = *(const f32x4*)&sK[sl][dg];
        const f32x4 vv4 = *(const f32x4*)&sV[sl][eg];
        acc0 += kv4[0] * vv4;
        acc1 += kv4[1] * vv4;
        acc2 += kv4[2] * vv4;
        acc3 += kv4[3] * vv4;
        ak4 += kv4;
      }
    } else {
#pragma unroll 4
      for (int sl = 0; sl < 32; ++sl) {
        const f32x4 kv4 = *(const f32x4*)&sK[sl][dg];
        const f32x4 vv4 = *(const f32x4*)&sV[sl][eg];
        acc0 += kv4[0] * vv4;
        acc1 += kv4[1] * vv4;
        acc2 += kv4[2] * vv4;
        acc3 += kv4[3] * vv4;
      }
    }
    __syncthreads();
  }
  float* outp = pkv + ((size_t)chunk * 64 + bh) * 4096;
  *(f32x4*)&outp[(dg + 0) * 64 + eg] = acc0;
  *(f32x4*)&outp[(dg + 1) * 64 + eg] = acc1;
  *(f32x4*)&outp[(dg + 2) * 64 + eg] = acc2;
  *(f32x4*)&outp[(dg + 3) * 64 + eg] = acc3;
  if (do_ks) *(f32x4*)&pks[((size_t)chunk * 64 + bh) * 64 + dg] = ak4;
}

// -------- merged: reduce partials -> kvn (LDS) -> W2T = wo @ kvn^T --------
// W2T[b][j][h*64+d] = sum_e wo[j][h*64+e] * kvn[bh][d][e],
// kvn[d][e] = (sum_c pkv)[d][e] / (ksum[e] + 1e-6).
// Reads w_out f32 DIRECTLY (sole consumer; same f2bf rounding as before).
// grid 64 (bh); block 256 (4 waves).
__global__ __launch_bounds__(256)
void kvw2t_kernel(const float* __restrict__ pkv, const float* __restrict__ pks,
                  const float* __restrict__ wo, u16* __restrict__ w2t) {
  const int bh = blockIdx.x, b = bh >> 4, h = bh & 15;
  const int t = threadIdx.x;
  __shared__ u16 skv[64][72];
  __shared__ float sks[64];
  __shared__ u16 sW[4][16 * 72];
  if (t < 64) {
    float s = 0.f;
    for (int c = 0; c < 8; ++c) s += pks[((size_t)c * 64 + bh) * 64 + t];
    sks[t] = s + 1e-6f;
  }
  __syncthreads();
#pragma unroll
  for (int j = 0; j < 16; ++j) {
    const int idx = t + j * 256;  // = d*64 + e
    float s = 0.f;
    for (int c = 0; c < 8; ++c) s += pkv[((size_t)c * 64 + bh) * 4096 + idx];
    skv[idx >> 6][idx & 63] = f2bf(s / sks[idx & 63]);
  }
  __syncthreads();
  const int wave = t >> 6, lane = t & 63;
  const int fr = lane & 15, fq = lane >> 4;
  // B frags (kvn as B of C=A*B^T): row=d=nn*16+fr, k=e contiguous 16B
  bf16x8 bfr[4][2];
#pragma unroll
  for (int ks = 0; ks < 2; ++ks)
#pragma unroll
    for (int nn = 0; nn < 4; ++nn)
      bfr[nn][ks] = *(const bf16x8*)&skv[nn * 16 + fr][ks * 32 + fq * 8];
  u16* wb = &sW[wave][0];
  u16* op = w2t + (size_t)b * 1048576 + h * 64;
  const int lrow = lane >> 3, lcol = (lane & 7) * 8;
#pragma unroll
  for (int st = 0; st < 4; ++st) {
    const int j0 = st * 256 + wave * 64;
#pragma unroll
    for (int mm = 0; mm < 4; ++mm) {
      f32x4 acc[4] = {};
#pragma unroll
      for (int ks = 0; ks < 2; ++ks) {
        const float* wp = &wo[(size_t)(j0 + mm * 16 + fr) * 1024 + h * 64 + ks * 32 + fq * 8];
        f32x4 wlo = *(const f32x4*)wp;
        f32x4 whi = *(const f32x4*)(wp + 4);
        u16x8 au;
#pragma unroll
        for (int j = 0; j < 4; ++j) { au[j] = f2bf(wlo[j]); au[4 + j] = f2bf(whi[j]); }
        bf16x8 af = __builtin_bit_cast(bf16x8, au);
#pragma unroll
        for (int nn = 0; nn < 4; ++nn)
          acc[nn] = __builtin_amdgcn_mfma_f32_16x16x32_bf16(af, bfr[nn][ks], acc[nn], 0, 0, 0);
      }
#pragma unroll
      for (int nn = 0; nn < 4; ++nn)
#pragma unroll
        for (int r = 0; r < 4; ++r)
          wb[(fq * 4 + r) * 72 + nn * 16 + fr] = f2bf(acc[nn][r]);
      // per-wave LDS in-order: read-back safe without barrier
#pragma unroll
      for (int i = 0; i < 2; ++i) {
        bf16x8 val = *(const bf16x8*)&wb[(i * 8 + lrow) * 72 + lcol];
        *(bf16x8*)&op[(size_t)(j0 + mm * 16 + i * 8 + lrow) * 1024 + lcol] = val;
      }
    }
  }
}

// -------------------------------------------------------------------------
extern "C" void kernel_launch(void* const* d_in, const int* in_sizes, int n_in,
                              void* d_out, int out_size, void* d_ws, size_t ws_size,
                              hipStream_t stream) {
  const float* x     = (const float*)d_in[0];
  const float* w_qkv = (const float*)d_in[1];
  const float* b_qkv = (const float*)d_in[2];
  const float* w_out = (const float*)d_in[3];
  const float* b_out = (const float*)d_in[4];
  float* out = (float*)d_out;

  const int M = 16384, Dm = 1024, N3 = 3072;

  char* ws = (char*)d_ws;
  u16* xb     = (u16*)(ws);                    //  33,554,432 B
  u16* wqb    = (u16*)(ws + 33554432);         //   6,291,456 B
  u16* qkvb   = (u16*)(ws + 41943040);         // 100,663,296 B
  u16* w2t    = (u16*)(ws + 142606336);        //   8,388,608 B
  float* pkv  = (float*)(ws + 176160768);      //   8,388,608 B
  float* pks  = (float*)(ws + 184549376);      //     131,072 B

  cvt_all_kernel<<<19456, 256, 0, stream>>>(x, xb, w_qkv, wqb);

  // qkv projection + elu feature map
  gemm256<0><<<(M / 256) * (N3 / 256), 512, 0, stream>>>(
      xb, Dm, wqb, b_qkv, qkvb, N3, Dm, N3 / 256, 0);
  // kv state
  kv_state_kernel<<<dim3(64, 8), 256, 0, stream>>>(qkvb, pkv, pks);
  // reduce + normalize + fold kvn into w_out (per b,h)
  kvw2t_kernel<<<64, 256, 0, stream>>>(pkv, pks, w_out, w2t);
  // out = q' @ W2T^T + b_out   (A = qkvb cols 0..1023, lda=3072; B per batch)
  gemm256<1><<<(M / 256) * (Dm / 256), 512, 0, stream>>>(
      qkvb, N3, w2t, b_out, out, Dm, Dm, Dm / 256, 1 << 20);
}

// Round 13
// 219.571 us; speedup vs baseline: 1.1183x; 1.1183x over previous
//
#include <hip/hip_runtime.h>
#include <stdint.h>

typedef float f32x4 __attribute__((ext_vector_type(4)));
typedef __bf16 bf16x8 __attribute__((ext_vector_type(8)));
typedef unsigned short u16;
typedef u16 u16x8 __attribute__((ext_vector_type(8)));

__device__ __forceinline__ u16 f2bf(float f) {
  uint32_t u = __builtin_bit_cast(uint32_t, f);
  return (u16)((u + 0x7fffu + ((u >> 16) & 1u)) >> 16);
}
__device__ __forceinline__ float bf2f(u16 h) {
  uint32_t u = ((uint32_t)h) << 16;
  return __builtin_bit_cast(float, u);
}
__device__ __forceinline__ float elup1(float x) {
  return x > 0.f ? x + 1.f : __expf(x);
}
__device__ __forceinline__ void gll16(const void* g, void* l) {
  __builtin_amdgcn_global_load_lds(
      (const __attribute__((address_space(1))) unsigned int*)g,
      (__attribute__((address_space(3))) unsigned int*)l, 16, 0, 0);
}

#define BAR() __builtin_amdgcn_s_barrier()
#define VMC(n) asm volatile("s_waitcnt vmcnt(" #n ")" ::: "memory")

// ---------------- fused f32 -> bf16 conversion (all 3 tensors) -----------
__global__ void cvt_all_kernel(const float* __restrict__ x, u16* __restrict__ xb,
                               const float* __restrict__ wq, u16* __restrict__ wqb,
                               const float* __restrict__ wo, u16* __restrict__ wob) {
  int i = blockIdx.x * 256 + threadIdx.x;  // float4 index, 5242880 total
  const float* in;
  u16* out;
  if (i < 4194304) {
    in = x; out = xb;
  } else if (i < 4980736) {
    in = wq; out = wqb; i -= 4194304;
  } else {
    in = wo; out = wob; i -= 4980736;
  }
  float4 f = ((const float4*)in)[i];
  ushort4 o;
  o.x = f2bf(f.x); o.y = f2bf(f.y); o.z = f2bf(f.z); o.w = f2bf(f.w);
  ((ushort4*)out)[i] = o;
}

// ============ 256x256 bf16 GEMM  C[M,N] = A[M,K]*B[N,K]^T =================
// r8/r11 configuration (best measured: 906 TF, MfmaUtil 37.9%) — the
// m97-class plain-HIP plateau, reproduced across 6 schedule variants.
// 512 threads (8 waves, 2M x 4N; wave tile 128x64). BK=64. LDS 128 KiB
// (2 dbuf), one vmcnt(0)+barrier per K-tile, both A-half frag sets live,
// wave-parity-staggered A-half order.
// Swizzle: stored colbyte = logical colbyte ^ ((ldsrow&7)<<4); gll dest
// linear, source pre-swizzled (rule #21).
// lda parametrized (out-proj reads q' cols of qkvb, lda=3072).
// bstep: B advances per 16 M-tiles (per-batch W2T); 0 = shared B.
// EPI==0: qkv epilogue (bias + elu+1, bf16 store, LDS-coalesced)
// EPI==1: out epilogue (bias, f32 store)
template <int EPI>
__global__ __launch_bounds__(512, 2)
void gemm256(const u16* __restrict__ A, int lda, const u16* __restrict__ B,
             const float* __restrict__ bias, void* __restrict__ Cout,
             int N, int K, int nbj, int bstep) {
  __shared__ __align__(16) u16 lds[65536];  // 128 KiB
  const int tid = threadIdx.x;
  const int wave = tid >> 6, lane = tid & 63;
  const int fr = lane & 15, fq = lane >> 4;
  const int wm = wave >> 2, wn = wave & 3;

  // XCD-aware bijective block swizzle (grid % 8 == 0 by construction)
  const int nwg = gridDim.x;
  const int cpx = nwg >> 3;
  const int swz = (blockIdx.x & 7) * cpx + (blockIdx.x >> 3);
  const int bi = swz / nbj, bj = swz % nbj;

  const u16* Ab = A + (size_t)bi * 256 * lda;
  const u16* Bb = B + (size_t)(bi >> 4) * bstep + (size_t)bj * 256 * K;

  // staging geometry: per inst, thread covers LDS bytes i*8192+wave*1024+lane*16
  const int l8 = lane >> 3;                       // ldsrow & 7
  const int cswz = ((lane & 7) ^ l8) << 3;        // swizzled col offset (elements)
  const int r6 = wave * 8 + l8;                   // row within 64-row inst block

#define STAGE_A(d, h, k0)                                                      \
  { _Pragma("unroll")                                                          \
    for (int i_ = 0; i_ < 2; ++i_) {                                           \
      int gr_ = i_ * 128 + (h) * 64 + r6;                                      \
      gll16(Ab + (size_t)gr_ * lda + (k0) + cswz,                              \
            &lds[((d) * 32768 + (h) * 16384 + i_ * 8192 + wave * 1024) >> 1]); \
    } }

#define STAGE_B(d, h, k0)                                                      \
  { _Pragma("unroll")                                                          \
    for (int i_ = 0; i_ < 2; ++i_) {                                           \
      int r_ = i_ * 64 + r6;                                                   \
      int gr_ = (r_ >> 5) * 64 + (h) * 32 + (r_ & 31);                         \
      gll16(Bb + (size_t)gr_ * K + (k0) + cswz,                                \
            &lds[(65536 + (d) * 32768 + (h) * 16384 + i_ * 8192 + wave * 1024) >> 1]); \
    } }

#define STAGE_ALL(d, k0) \
  { STAGE_A(d, 0, k0); STAGE_A(d, 1, k0); STAGE_B(d, 0, k0); STAGE_B(d, 1, k0); }

  // fragment-read addressing (bytes)
  const int xorc = (fr & 7) << 4;
  const int acol[2] = {(fq * 16) ^ xorc, (64 + fq * 16) ^ xorc};
  const int arow = (wm * 64 + fr) * 128;
  const int brow = (wn * 32 + fr) * 128;

#define LDSV(off) (*(const bf16x8*)&lds[(off) >> 1])

  f32x4 acc[8][4] = {};
  bf16x8 af0[4][2], af1[4][2];  // BOTH A-halves live (no WAR with MFMA)
  bf16x8 bfr[2][2][2];          // B frags [nh][nn][ks], both halves live

#define READ_A(d, mh, dst)                                                     \
  { _Pragma("unroll")                                                          \
    for (int ks = 0; ks < 2; ++ks) {                                           \
      _Pragma("unroll")                                                        \
      for (int mm = 0; mm < 4; ++mm)                                           \
        dst[mm][ks] = LDSV((d) * 32768 + (mh) * 16384 + arow + mm * 2048 + acol[ks]); \
    } }

#define READ_B(d, nh)                                                          \
  { _Pragma("unroll")                                                          \
    for (int ks = 0; ks < 2; ++ks) {                                           \
      _Pragma("unroll")                                                        \
      for (int nn = 0; nn < 2; ++nn)                                           \
        bfr[nh][nn][ks] = LDSV(65536 + (d) * 32768 + (nh) * 16384 + brow + nn * 2048 + acol[ks]); \
    } }

#define MFMA_Q(mh, nh, src)                                                    \
  { __builtin_amdgcn_s_setprio(1);                                             \
    _Pragma("unroll")                                                          \
    for (int ks = 0; ks < 2; ++ks) {                                           \
      _Pragma("unroll")                                                        \
      for (int mm = 0; mm < 4; ++mm) {                                         \
        _Pragma("unroll")                                                      \
        for (int nn = 0; nn < 2; ++nn)                                         \
          acc[(mh) * 4 + mm][(nh) * 2 + nn] = __builtin_amdgcn_mfma_f32_16x16x32_bf16( \
              src[mm][ks], bfr[nh][nn][ks], acc[(mh) * 4 + mm][(nh) * 2 + nn], 0, 0, 0); \
      } }                                                                      \
    __builtin_amdgcn_s_setprio(0); }

  // F = first A-half computed, S = second; parity-staggered across waves.
#define TILE_BODY(F, S, afF, afS, d, t)                                        \
  {                                                                            \
    READ_B(d, 0); READ_B(d, 1); READ_A(d, F, afF);                             \
    MFMA_Q(F, 0, afF);                                                         \
    READ_A(d, S, afS);                                                         \
    MFMA_Q(F, 1, afF);                                                         \
    if ((t) + 1 < NT) STAGE_ALL((d) ^ 1, ((t) + 1) << 6);                      \
    MFMA_Q(S, 1, afS);                                                         \
    MFMA_Q(S, 0, afS);                                                         \
  }

  const int NT = K >> 6;
  STAGE_ALL(0, 0);
  VMC(0);
  BAR();

  if ((wave & 1) == 0) {
    for (int t = 0; t < NT; ++t) {
      const int d = t & 1;
      TILE_BODY(0, 1, af0, af1, d, t);
      VMC(0); BAR();
    }
  } else {
    for (int t = 0; t < NT; ++t) {
      const int d = t & 1;
      TILE_BODY(1, 0, af1, af0, d, t);
      VMC(0); BAR();
    }
  }

  // ---- epilogue
  const int wrow = wm * 128, wcol = wn * 64;
  if (EPI == 0) {
    const bool do_elu = (bj * 256) < 2048;  // 2048 is 256-aligned
    float bv[4];
#pragma unroll
    for (int n = 0; n < 4; ++n) bv[n] = bias[bj * 256 + wcol + n * 16 + fr];
    u16* wbuf = &lds[wave * 8192];  // wave-private 16 KiB
    const int lrow = lane >> 3, lcol = (lane & 7) * 8;
#pragma unroll
    for (int ch = 0; ch < 2; ++ch) {
#pragma unroll
      for (int m2 = 0; m2 < 4; ++m2)
#pragma unroll
        for (int n = 0; n < 4; ++n)
#pragma unroll
          for (int r = 0; r < 4; ++r) {
            float v = acc[ch * 4 + m2][n][r] + bv[n];
            if (do_elu) v = elup1(v);
            wbuf[(m2 * 16 + fq * 4 + r) * 72 + n * 16 + fr] = f2bf(v);
          }
      // per-wave LDS in-order: read-back safe without barrier
#pragma unroll
      for (int i = 0; i < 8; ++i) {
        bf16x8 val = *(const bf16x8*)&wbuf[(i * 8 + lrow) * 72 + lcol];
        const int rowg = bi * 256 + wrow + ch * 64 + i * 8 + lrow;
        *(bf16x8*)&((u16*)Cout)[(size_t)rowg * N + bj * 256 + wcol + lcol] = val;
      }
    }
  } else {
#pragma unroll
    for (int n = 0; n < 4; ++n) {
      const int colg = bj * 256 + wcol + n * 16 + fr;
      const float bv = bias[colg];
#pragma unroll
      for (int m = 0; m < 8; ++m)
#pragma unroll
        for (int r = 0; r < 4; ++r) {
          const int rowg = bi * 256 + wrow + m * 16 + fq * 4 + r;
          ((float*)Cout)[(size_t)rowg * N + colg] = acc[m][n][r] + bv;
        }
    }
  }
#undef STAGE_A
#undef STAGE_B
#undef STAGE_ALL
#undef READ_A
#undef READ_B
#undef MFMA_Q
#undef TILE_BODY
#undef LDSV
}

// ---------------- kv state partials: kv[d][e] = sum_s k[s,d]*v[s,e] -------
// grid: (64 bh, 8 s-chunks of 512); block 256; 4d x 4e register blocking.
// 32-row LDS tiles. ksum accumulated only by wave 0 (WAVE-UNIFORM branch:
// whole wave takes one side; no divergence) — waves 1-3 skip 4/20 VALU ops.
__global__ __launch_bounds__(256)
void kv_state_kernel(const u16* __restrict__ qkv, float* __restrict__ pkv,
                     float* __restrict__ pks) {
  const int bh = blockIdx.x, chunk = blockIdx.y;
  const int b = bh >> 4, h = bh & 15;
  const int t = threadIdx.x;
  __shared__ float sK[32][68];
  __shared__ float sV[32][68];
  const int dg = (t & 15) * 4;
  const int eg = (t >> 4) * 4;
  f32x4 acc0 = {}, acc1 = {}, acc2 = {}, acc3 = {};
  f32x4 ak4 = {};
  const size_t rowbase = ((size_t)b * 4096 + (size_t)chunk * 512) * 3072;
  const u16* kp = qkv + rowbase + 1024 + h * 64;
  const u16* vp = qkv + rowbase + 2048 + h * 64;
  // staging: 128 threads K, 128 threads V; 2 x 16B/lane per 32-row tile
  const int lhalf = t >> 7, lr = (t >> 3) & 15, lc = (t & 7) * 8;
  const u16* lsrc = lhalf ? vp : kp;
  float* ldst = lhalf ? &sV[lr][lc] : &sK[lr][lc];
  const bool wave0 = (t < 64);  // wave-uniform
  for (int s0 = 0; s0 < 512; s0 += 32) {
    u16x8 v8a = *(const u16x8*)&lsrc[(size_t)(s0 + lr) * 3072 + lc];
    u16x8 v8b = *(const u16x8*)&lsrc[(size_t)(s0 + 16 + lr) * 3072 + lc];
#pragma unroll
    for (int j = 0; j < 8; ++j) ldst[j] = bf2f(v8a[j]);
#pragma unroll
    for (int j = 0; j < 8; ++j) ldst[16 * 68 + j] = bf2f(v8b[j]);
    __syncthreads();
    if (wave0) {
#pragma unroll 4
      for (int sl = 0; sl < 32; ++sl) {
        const f32x4 kv4 = *(const f32x4*)&sK[sl][dg];
        const f32x4 vv4 = *(const f32x4*)&sV[sl][eg];
        acc0 += kv4[0] * vv4;
        acc1 += kv4[1] * vv4;
        acc2 += kv4[2] * vv4;
        acc3 += kv4[3] * vv4;
        ak4 += kv4;
      }
    } else {
#pragma unroll 4
      for (int sl = 0; sl < 32; ++sl) {
        const f32x4 kv4 = *(const f32x4*)&sK[sl][dg];
        const f32x4 vv4 = *(const f32x4*)&sV[sl][eg];
        acc0 += kv4[0] * vv4;
        acc1 += kv4[1] * vv4;
        acc2 += kv4[2] * vv4;
        acc3 += kv4[3] * vv4;
      }
    }
    __syncthreads();
  }
  float* outp = pkv + ((size_t)chunk * 64 + bh) * 4096;
  *(f32x4*)&outp[(dg + 0) * 64 + eg] = acc0;
  *(f32x4*)&outp[(dg + 1) * 64 + eg] = acc1;
  *(f32x4*)&outp[(dg + 2) * 64 + eg] = acc2;
  *(f32x4*)&outp[(dg + 3) * 64 + eg] = acc3;
  if (t < 16) *(f32x4*)&pks[((size_t)chunk * 64 + bh) * 64 + dg] = ak4;
}

// -------- merged: reduce partials -> kvn (LDS) -> W2T = wo @ kvn^T --------
// W2T[b][j][h*64+d] = sum_e wo[j][h*64+e] * kvn[bh][d][e],
// kvn[d][e] = (sum_c pkv)[d][e] / (ksum[e] + 1e-6).
// grid 64 (bh); block 256 (4 waves). Phase 1: reduce into padded LDS (bf16,
// row stride 72 u16 -> 2-way-free banking). Phase 2: each wave 4 strips of
// 64 j-rows (128 MFMA/wave), LDS-coalesced bf16 store.
__global__ __launch_bounds__(256)
void kvw2t_kernel(const float* __restrict__ pkv, const float* __restrict__ pks,
                  const u16* __restrict__ wob, u16* __restrict__ w2t) {
  const int bh = blockIdx.x, b = bh >> 4, h = bh & 15;
  const int t = threadIdx.x;
  __shared__ u16 skv[64][72];
  __shared__ float sks[64];
  __shared__ u16 sW[4][16 * 72];
  if (t < 64) {
    float s = 0.f;
    for (int c = 0; c < 8; ++c) s += pks[((size_t)c * 64 + bh) * 64 + t];
    sks[t] = s + 1e-6f;
  }
  __syncthreads();
#pragma unroll
  for (int j = 0; j < 16; ++j) {
    const int idx = t + j * 256;  // = d*64 + e
    float s = 0.f;
    for (int c = 0; c < 8; ++c) s += pkv[((size_t)c * 64 + bh) * 4096 + idx];
    skv[idx >> 6][idx & 63] = f2bf(s / sks[idx & 63]);
  }
  __syncthreads();
  const int wave = t >> 6, lane = t & 63;
  const int fr = lane & 15, fq = lane >> 4;
  // B frags (kvn as B of C=A*B^T): row=d=nn*16+fr, k=e contiguous 16B
  bf16x8 bfr[4][2];
#pragma unroll
  for (int ks = 0; ks < 2; ++ks)
#pragma unroll
    for (int nn = 0; nn < 4; ++nn)
      bfr[nn][ks] = *(const bf16x8*)&skv[nn * 16 + fr][ks * 32 + fq * 8];
  u16* wb = &sW[wave][0];
  u16* op = w2t + (size_t)b * 1048576 + h * 64;
  const int lrow = lane >> 3, lcol = (lane & 7) * 8;
#pragma unroll
  for (int st = 0; st < 4; ++st) {
    const int j0 = st * 256 + wave * 64;
#pragma unroll
    for (int mm = 0; mm < 4; ++mm) {
      f32x4 acc[4] = {};
#pragma unroll
      for (int ks = 0; ks < 2; ++ks) {
        bf16x8 af = *(const bf16x8*)&wob[(size_t)(j0 + mm * 16 + fr) * 1024 + h * 64 + ks * 32 + fq * 8];
#pragma unroll
        for (int nn = 0; nn < 4; ++nn)
          acc[nn] = __builtin_amdgcn_mfma_f32_16x16x32_bf16(af, bfr[nn][ks], acc[nn], 0, 0, 0);
      }
#pragma unroll
      for (int nn = 0; nn < 4; ++nn)
#pragma unroll
        for (int r = 0; r < 4; ++r)
          wb[(fq * 4 + r) * 72 + nn * 16 + fr] = f2bf(acc[nn][r]);
      // per-wave LDS in-order: read-back safe without barrier
#pragma unroll
      for (int i = 0; i < 2; ++i) {
        bf16x8 val = *(const bf16x8*)&wb[(i * 8 + lrow) * 72 + lcol];
        *(bf16x8*)&op[(size_t)(j0 + mm * 16 + i * 8 + lrow) * 1024 + lcol] = val;
      }
    }
  }
}

// -------------------------------------------------------------------------
extern "C" void kernel_launch(void* const* d_in, const int* in_sizes, int n_in,
                              void* d_out, int out_size, void* d_ws, size_t ws_size,
                              hipStream_t stream) {
  const float* x     = (const float*)d_in[0];
  const float* w_qkv = (const float*)d_in[1];
  const float* b_qkv = (const float*)d_in[2];
  const float* w_out = (const float*)d_in[3];
  const float* b_out = (const float*)d_in[4];
  float* out = (float*)d_out;

  const int M = 16384, Dm = 1024, N3 = 3072;

  char* ws = (char*)d_ws;
  u16* xb     = (u16*)(ws);                    //  33,554,432 B
  u16* wqb    = (u16*)(ws + 33554432);         //   6,291,456 B
  u16* wob    = (u16*)(ws + 39845888);         //   2,097,152 B
  u16* qkvb   = (u16*)(ws + 41943040);         // 100,663,296 B
  u16* w2t    = (u16*)(ws + 142606336);        //   8,388,608 B
  float* pkv  = (float*)(ws + 176160768);      //   8,388,608 B
  float* pks  = (float*)(ws + 184549376);      //     131,072 B

  cvt_all_kernel<<<20480, 256, 0, stream>>>(x, xb, w_qkv, wqb, w_out, wob);

  // qkv projection + elu feature map
  gemm256<0><<<(M / 256) * (N3 / 256), 512, 0, stream>>>(
      xb, Dm, wqb, b_qkv, qkvb, N3, Dm, N3 / 256, 0);
  // kv state
  kv_state_kernel<<<dim3(64, 8), 256, 0, stream>>>(qkvb, pkv, pks);
  // reduce + normalize + fold kvn into w_out (per b,h)
  kvw2t_kernel<<<64, 256, 0, stream>>>(pkv, pks, wob, w2t);
  // out = q' @ W2T^T + b_out   (A = qkvb cols 0..1023, lda=3072; B per batch)
  gemm256<1><<<(M / 256) * (Dm / 256), 512, 0, stream>>>(
      qkvb, N3, w2t, b_out, out, Dm, Dm, Dm / 256, 1 << 20);
}